// Round 2
// baseline (3931.537 us; speedup 1.0000x reference)
//
#include <hip/hip_runtime.h>
#include <hip/hip_bf16.h>

// Problem constants
#define TT 4096      // tokens = B*L
#define DD 1024      // model dim
#define EE 8         // experts
#define HH 4096      // mlp hidden
#define KSEL 24576   // expert_k = B*L*CAPACITY (1-indexed kth smallest)

using f32x4 = __attribute__((ext_vector_type(4))) float;
using s16x8 = __attribute__((ext_vector_type(8))) short;

__device__ __forceinline__ unsigned short f2bf(float f) {
    unsigned int u = __float_as_uint(f);
    unsigned int r = u + 0x7FFFu + ((u >> 16) & 1u);
    return (unsigned short)(r >> 16);
}

__device__ __forceinline__ float gelu_tanh(float v) {
    float v3 = v * v * v;
    return 0.5f * v * (1.0f + tanhf(0.7978845608028654f * (v + 0.044715f * v3)));
}

__device__ __forceinline__ s16x8 cvt8(float4 a, float4 b) {
    s16x8 r;
    r[0] = (short)f2bf(a.x); r[1] = (short)f2bf(a.y);
    r[2] = (short)f2bf(a.z); r[3] = (short)f2bf(a.w);
    r[4] = (short)f2bf(b.x); r[5] = (short)f2bf(b.y);
    r[6] = (short)f2bf(b.z); r[7] = (short)f2bf(b.w);
    return r;
}

// ---------------- Kernel 1: router logits [T][E] fp32 ----------------
__global__ void k_logits(const float* __restrict__ x, const float* __restrict__ gw,
                         float* __restrict__ logits) {
    int wid = threadIdx.x >> 6, lane = threadIdx.x & 63;
    int t = blockIdx.x * 4 + wid;
    if (t >= TT) return;
    const float* xr = x + (size_t)t * DD;
    float acc[EE];
#pragma unroll
    for (int e = 0; e < EE; ++e) acc[e] = 0.f;
    for (int i = 0; i < DD / 64; ++i) {
        int d = i * 64 + lane;
        float xv = xr[d];
#pragma unroll
        for (int e = 0; e < EE; ++e) acc[e] += xv * gw[e * DD + d];
    }
#pragma unroll
    for (int e = 0; e < EE; ++e) {
        float v = acc[e];
        for (int off = 32; off; off >>= 1) v += __shfl_xor(v, off, 64);
        if (lane == 0) logits[(size_t)t * EE + e] = v;
    }
}

// ---------------- Kernel 2: exact kth smallest (k=KSEL) ----------------
__global__ void k_select(const float* __restrict__ logits, float* __restrict__ kth) {
    int tid = threadIdx.x;           // 1024 threads
    unsigned int v[32];
#pragma unroll
    for (int i = 0; i < 32; ++i) {
        unsigned int b = __float_as_uint(logits[tid + i * 1024]);
        v[i] = (b & 0x80000000u) ? ~b : (b | 0x80000000u);
    }
    __shared__ int s_cnt;
    unsigned int prefix = 0;
    for (int bit = 31; bit >= 0; --bit) {
        unsigned int cand = prefix | (1u << bit);
        int c = 0;
#pragma unroll
        for (int i = 0; i < 32; ++i) c += (v[i] < cand) ? 1 : 0;
        for (int off = 32; off; off >>= 1) c += __shfl_xor(c, off, 64);
        __syncthreads();                       // previous iter's read done
        if (tid == 0) s_cnt = 0;
        __syncthreads();
        if ((tid & 63) == 0) atomicAdd(&s_cnt, c);
        __syncthreads();
        if (s_cnt < KSEL) prefix = cand;       // kth >= cand -> bit is 1
    }
    if (tid == 0) {
        unsigned int b = (prefix & 0x80000000u) ? (prefix ^ 0x80000000u) : ~prefix;
        *kth = __uint_as_float(b);
    }
}

// ---------------- Kernel 3: per-expert compact token lists ----------------
__global__ void k_lists(const float* __restrict__ logits, const float* __restrict__ kth,
                        int* __restrict__ cnt, int* __restrict__ toks,
                        float* __restrict__ gates) {
    int idx = blockIdx.x * 256 + threadIdx.x;      // idx over [T][E]
    float v = logits[idx];
    if (v >= *kth) {
        int e = idx & 7, t = idx >> 3;
        int p = atomicAdd(&cnt[e], 1);
        toks[e * TT + p] = t;
        gates[e * TT + p] = v;
    }
}

// ---------------- Kernel 4: fused expert MLP ----------------
// grid = (64 token-tiles, E experts, 2 H-halves), 512 threads (8 waves)
// per block: tokens tile [64], output acc [64 x 1024] fp32 in regs,
// loop 32 H-chunks of 64: GEMM1 (K=1024) -> gelu -> h_lds bf16 -> GEMM2 accumulate.
__global__ __launch_bounds__(512, 2) void k_moe(
    const float* __restrict__ x, const float* __restrict__ w1,
    const float* __restrict__ b1, const float* __restrict__ w2,
    const float* __restrict__ b2, const int* __restrict__ cnt,
    const int* __restrict__ toks, const float* __restrict__ gates,
    float* __restrict__ out) {
    int e = blockIdx.y;
    int c = cnt[e];
    int m0 = blockIdx.x * 64;
    if (m0 >= c) return;
    int n = min(64, c - m0);

    __shared__ unsigned short h_lds[64][72];   // bf16 bits, +8 pad
    __shared__ int s_tok[64];
    __shared__ float s_gate[64];

    int tidx = threadIdx.x;
    if (tidx < 64) {
        s_tok[tidx]  = (tidx < n) ? toks[e * TT + m0 + tidx] : 0;
        s_gate[tidx] = (tidx < n) ? gates[e * TT + m0 + tidx] : 0.f;
    }
    __syncthreads();

    int w = tidx >> 6, lane = tidx & 63;
    int l15 = lane & 15, l4 = lane >> 4;
    // GEMM1 wave roles: h-tile [64 tok x 64 H] = 4x4 frags; wave w owns frags (hm..hm+1, hn)
    int hm = (w >> 2) * 2;
    int hn = w & 3;
    int arow0 = hm * 16 + l15, arow1 = arow0 + 16;
    const float* xr0 = x + (size_t)s_tok[arow0] * DD;
    const float* xr1 = x + (size_t)s_tok[arow1] * DD;
    // GEMM2: wave w owns out cols [w*128, +128)
    int nbase = w * 128;

    f32x4 acc[4][8];
#pragma unroll
    for (int mf = 0; mf < 4; ++mf)
#pragma unroll
        for (int nf = 0; nf < 8; ++nf) acc[mf][nf] = (f32x4){0.f, 0.f, 0.f, 0.f};

    int hc0 = blockIdx.z * 32;
    for (int hc = hc0; hc < hc0 + 32; ++hc) {
        int hbase = hc * 64;
        // ---- GEMM1: h[64x64] = X[64x1024] @ w1[e][hbase..+64][1024]^T ----
        f32x4 hacc0 = {0.f, 0.f, 0.f, 0.f}, hacc1 = {0.f, 0.f, 0.f, 0.f};
        const float* w1r = w1 + ((size_t)e * HH + hbase + hn * 16 + l15) * DD;
#pragma unroll 4
        for (int ks = 0; ks < 32; ++ks) {
            int kk = ks * 32 + l4 * 8;
            s16x8 a0 = cvt8(*(const float4*)(xr0 + kk), *(const float4*)(xr0 + kk + 4));
            s16x8 a1 = cvt8(*(const float4*)(xr1 + kk), *(const float4*)(xr1 + kk + 4));
            s16x8 bb = cvt8(*(const float4*)(w1r + kk), *(const float4*)(w1r + kk + 4));
            hacc0 = __builtin_amdgcn_mfma_f32_16x16x32_bf16(a0, bb, hacc0, 0, 0, 0);
            hacc1 = __builtin_amdgcn_mfma_f32_16x16x32_bf16(a1, bb, hacc1, 0, 0, 0);
        }
        // bias + gelu -> h_lds (D-frag: col=lane&15, row=(lane>>4)*4+j)
        int hcol = hn * 16 + l15;
        float bias = b1[(size_t)e * HH + hbase + hcol];
#pragma unroll
        for (int j = 0; j < 4; ++j) {
            int r0 = hm * 16 + l4 * 4 + j;
            h_lds[r0][hcol]      = f2bf(gelu_tanh(hacc0[j] + bias));
            h_lds[r0 + 16][hcol] = f2bf(gelu_tanh(hacc1[j] + bias));
        }
        __syncthreads();
        // ---- GEMM2: acc[64 x 1024] += h[64x64] @ w2[e][:, hbase..+64]^T ----
#pragma unroll
        for (int k2 = 0; k2 < 2; ++k2) {
            int kk = k2 * 32 + l4 * 8;
            s16x8 ha[4];
#pragma unroll
            for (int mf = 0; mf < 4; ++mf)
                ha[mf] = *(const s16x8*)(&h_lds[mf * 16 + l15][kk]);
#pragma unroll
            for (int nf = 0; nf < 8; ++nf) {
                const float* w2r =
                    w2 + ((size_t)e * DD + nbase + nf * 16 + l15) * HH + hbase + kk;
                s16x8 bb = cvt8(*(const float4*)(w2r), *(const float4*)(w2r + 4));
#pragma unroll
                for (int mf = 0; mf < 4; ++mf)
                    acc[mf][nf] =
                        __builtin_amdgcn_mfma_f32_16x16x32_bf16(ha[mf], bb, acc[mf][nf], 0, 0, 0);
            }
        }
        __syncthreads();
    }
    // ---- epilogue: out[t][col] += gate * (y + b2) ----
    bool add_b2 = (blockIdx.z == 0);
#pragma unroll
    for (int mf = 0; mf < 4; ++mf) {
#pragma unroll
        for (int j = 0; j < 4; ++j) {
            int row = mf * 16 + l4 * 4 + j;
            if (row < n) {
                float g = s_gate[row];
                int t = s_tok[row];
#pragma unroll
                for (int nf = 0; nf < 8; ++nf) {
                    int col = nbase + nf * 16 + l15;
                    float val = acc[mf][nf][j];
                    if (add_b2) val += b2[(size_t)e * DD + col];
                    atomicAdd(&out[(size_t)t * DD + col], g * val);
                }
            }
        }
    }
}

extern "C" void kernel_launch(void* const* d_in, const int* in_sizes, int n_in,
                              void* d_out, int out_size, void* d_ws, size_t ws_size,
                              hipStream_t stream) {
    const float* x  = (const float*)d_in[0];
    const float* gw = (const float*)d_in[1];
    const float* w1 = (const float*)d_in[2];
    const float* b1 = (const float*)d_in[3];
    const float* w2 = (const float*)d_in[4];
    const float* b2 = (const float*)d_in[5];
    float* out = (float*)d_out;

    char* ws = (char*)d_ws;
    float* logits = (float*)ws;                  // 32768 f  = 131072 B
    float* kth    = (float*)(ws + 131072);       // 1 f
    int*   cnt    = (int*)(ws + 131104);         // 8 i
    int*   toks   = (int*)(ws + 131136);         // 8*4096 i = 131072 B
    float* gates  = (float*)(ws + 262208);       // 8*4096 f = 131072 B

    hipMemsetAsync(out, 0, (size_t)TT * DD * sizeof(float), stream);
    hipMemsetAsync(cnt, 0, EE * sizeof(int), stream);

    k_logits<<<dim3(TT / 4), dim3(256), 0, stream>>>(x, gw, logits);
    k_select<<<dim3(1), dim3(1024), 0, stream>>>(logits, kth);
    k_lists<<<dim3(TT * EE / 256), dim3(256), 0, stream>>>(logits, kth, cnt, toks, gates);
    k_moe<<<dim3(64, EE, 2), dim3(512), 0, stream>>>(x, w1, b1, w2, b2, cnt, toks, gates, out);
}

// Round 3
// 816.973 us; speedup vs baseline: 4.8123x; 4.8123x over previous
//
#include <hip/hip_runtime.h>
#include <hip/hip_bf16.h>

// Problem constants
#define TT 4096      // tokens = B*L
#define DD 1024      // model dim
#define EE 8         // experts
#define HH 4096      // mlp hidden
#define KSEL 24576   // expert_k (1-indexed kth smallest)
#define HS  1536     // h_ws rows per expert (c_e ~ 1024 +- ~50; 1536 is >10 sigma)

using f32x4 = __attribute__((ext_vector_type(4))) float;
using s16x8 = __attribute__((ext_vector_type(8))) short;

__device__ __forceinline__ unsigned short f2bf(float f) {
    unsigned int u = __float_as_uint(f);
    unsigned int r = u + 0x7FFFu + ((u >> 16) & 1u);
    return (unsigned short)(r >> 16);
}

__device__ __forceinline__ float gelu_tanh(float v) {
    float v3 = v * v * v;
    return 0.5f * v * (1.0f + tanhf(0.7978845608028654f * (v + 0.044715f * v3)));
}

__device__ __forceinline__ s16x8 cvt8(float4 a, float4 b) {
    s16x8 r;
    r[0] = (short)f2bf(a.x); r[1] = (short)f2bf(a.y);
    r[2] = (short)f2bf(a.z); r[3] = (short)f2bf(a.w);
    r[4] = (short)f2bf(b.x); r[5] = (short)f2bf(b.y);
    r[6] = (short)f2bf(b.z); r[7] = (short)f2bf(b.w);
    return r;
}

// ---------------- Kernel 1: router logits [T][E] fp32 ----------------
__global__ void k_logits(const float* __restrict__ x, const float* __restrict__ gw,
                         float* __restrict__ logits) {
    int wid = threadIdx.x >> 6, lane = threadIdx.x & 63;
    int t = blockIdx.x * 4 + wid;
    if (t >= TT) return;
    const float* xr = x + (size_t)t * DD;
    float acc[EE];
#pragma unroll
    for (int e = 0; e < EE; ++e) acc[e] = 0.f;
    for (int i = 0; i < DD / 64; ++i) {
        int d = i * 64 + lane;
        float xv = xr[d];
#pragma unroll
        for (int e = 0; e < EE; ++e) acc[e] += xv * gw[e * DD + d];
    }
#pragma unroll
    for (int e = 0; e < EE; ++e) {
        float v = acc[e];
        for (int off = 32; off; off >>= 1) v += __shfl_xor(v, off, 64);
        if (lane == 0) logits[(size_t)t * EE + e] = v;
    }
}

// ---------------- Kernel 2: exact kth smallest (k=KSEL) ----------------
__global__ void k_select(const float* __restrict__ logits, float* __restrict__ kth) {
    int tid = threadIdx.x;           // 1024 threads
    unsigned int v[32];
#pragma unroll
    for (int i = 0; i < 32; ++i) {
        unsigned int b = __float_as_uint(logits[tid + i * 1024]);
        v[i] = (b & 0x80000000u) ? ~b : (b | 0x80000000u);
    }
    __shared__ int s_cnt;
    unsigned int prefix = 0;
    for (int bit = 31; bit >= 0; --bit) {
        unsigned int cand = prefix | (1u << bit);
        int c = 0;
#pragma unroll
        for (int i = 0; i < 32; ++i) c += (v[i] < cand) ? 1 : 0;
        for (int off = 32; off; off >>= 1) c += __shfl_xor(c, off, 64);
        __syncthreads();
        if (tid == 0) s_cnt = 0;
        __syncthreads();
        if ((tid & 63) == 0) atomicAdd(&s_cnt, c);
        __syncthreads();
        if (s_cnt < KSEL) prefix = cand;
    }
    if (tid == 0) {
        unsigned int b = (prefix & 0x80000000u) ? (prefix ^ 0x80000000u) : ~prefix;
        *kth = __uint_as_float(b);
    }
}

// ---------------- Kernel 3: per-expert compact token lists ----------------
__global__ void k_lists(const float* __restrict__ logits, const float* __restrict__ kth,
                        int* __restrict__ cnt, int* __restrict__ toks,
                        float* __restrict__ gates) {
    int idx = blockIdx.x * 256 + threadIdx.x;      // idx over [T][E]
    float v = logits[idx];
    if (v >= *kth) {
        int e = idx & 7, t = idx >> 3;
        int p = atomicAdd(&cnt[e], 1);
        if (p < TT) { toks[e * TT + p] = t; gates[e * TT + p] = v; }
    }
}

// ================= GEMM common =================
// 128x128 tile, BK=32, 256 threads = 4 waves; wave quadrant 64x64.
// LDS tiles swizzled: row byte-stride 64, byte = r*64 + (chunk16 ^ ((r&3)<<4)).
// A-frag (16x16x32): lane reads row (l&15), k-chunk (l>>4) -> 2-way conflict (free).

#define SWZ_W(r, cb) ((r) * 64 + ((cb) ^ (((r) & 3) << 4)))

// ---------------- Kernel 4: GEMM1 + gelu -> h_ws (bf16) ----------------
// grid (12 m-tiles, 32 n-tiles, 8 experts), 256 threads
__global__ __launch_bounds__(256, 2) void k_mlp1(
    const float* __restrict__ x, const float* __restrict__ w1,
    const float* __restrict__ b1, const int* __restrict__ cnt,
    const int* __restrict__ toks, unsigned short* __restrict__ h_ws) {
    int e = blockIdx.z;
    int c = cnt[e];
    int m0 = blockIdx.x * 128;
    if (m0 >= c) return;
    int n0 = blockIdx.y * 128;

    __shared__ char sA[2][8192];
    __shared__ char sB[2][8192];

    int tid = threadIdx.x;
    int w = tid >> 6, lane = tid & 63;
    int l15 = lane & 15, l4 = lane >> 4;
    int wrow = (w >> 1) * 64, wcol = (w & 1) * 64;

    // staging roles: thread stages one half-row (16 elems) of A and of B
    int ra = tid >> 1, ha = tid & 1;
    int ptok = m0 + ra;
    int tok = (ptok < c) ? toks[e * TT + ptok] : 0;
    const float* srcA = x + (size_t)tok * DD + ha * 16;
    const float* srcB = w1 + ((size_t)e * HH + n0 + ra) * DD + ha * 16;
    int wbyteA0 = SWZ_W(ra, ha * 32);
    int wbyteA1 = SWZ_W(ra, ha * 32 + 16);

    f32x4 acc[4][4];
#pragma unroll
    for (int mf = 0; mf < 4; ++mf)
#pragma unroll
        for (int nf = 0; nf < 4; ++nf) acc[mf][nf] = (f32x4){0.f, 0.f, 0.f, 0.f};

    // read addresses (swizzle folds to (l4 ^ (l15&3))*16)
    int rchunk = ((l4 ^ (l15 & 3)) * 16);

    float4 la[4], lb[4];
#pragma unroll
    for (int q = 0; q < 4; ++q) { la[q] = ((const float4*)srcA)[q]; lb[q] = ((const float4*)srcB)[q]; }
    *(s16x8*)(&sA[0][wbyteA0]) = cvt8(la[0], la[1]);
    *(s16x8*)(&sA[0][wbyteA1]) = cvt8(la[2], la[3]);
    *(s16x8*)(&sB[0][wbyteA0]) = cvt8(lb[0], lb[1]);
    *(s16x8*)(&sB[0][wbyteA1]) = cvt8(lb[2], lb[3]);
    __syncthreads();

    const int NS = DD / 32;   // 32 K-steps
    for (int s = 0; s < NS; ++s) {
        if (s + 1 < NS) {
            const float* pa = srcA + (s + 1) * 32;
            const float* pb = srcB + (s + 1) * 32;
#pragma unroll
            for (int q = 0; q < 4; ++q) { la[q] = ((const float4*)pa)[q]; lb[q] = ((const float4*)pb)[q]; }
        }
        int buf = s & 1;
        s16x8 af[4], bf[4];
#pragma unroll
        for (int mf = 0; mf < 4; ++mf) {
            int r = wrow + mf * 16 + l15;
            af[mf] = *(const s16x8*)(&sA[buf][r * 64 + rchunk]);
        }
#pragma unroll
        for (int nf = 0; nf < 4; ++nf) {
            int r = wcol + nf * 16 + l15;
            bf[nf] = *(const s16x8*)(&sB[buf][r * 64 + rchunk]);
        }
#pragma unroll
        for (int mf = 0; mf < 4; ++mf)
#pragma unroll
            for (int nf = 0; nf < 4; ++nf)
                acc[mf][nf] = __builtin_amdgcn_mfma_f32_16x16x32_bf16(af[mf], bf[nf], acc[mf][nf], 0, 0, 0);
        if (s + 1 < NS) {
            int nb = buf ^ 1;
            *(s16x8*)(&sA[nb][wbyteA0]) = cvt8(la[0], la[1]);
            *(s16x8*)(&sA[nb][wbyteA1]) = cvt8(la[2], la[3]);
            *(s16x8*)(&sB[nb][wbyteA0]) = cvt8(lb[0], lb[1]);
            *(s16x8*)(&sB[nb][wbyteA1]) = cvt8(lb[2], lb[3]);
        }
        __syncthreads();
    }

    // epilogue: h = gelu(acc + b1) -> h_ws bf16 (pad rows written too, harmless)
#pragma unroll
    for (int nf = 0; nf < 4; ++nf) {
        int hcol = n0 + wcol + nf * 16 + l15;
        float bias = b1[(size_t)e * HH + hcol];
#pragma unroll
        for (int mf = 0; mf < 4; ++mf) {
#pragma unroll
            for (int j = 0; j < 4; ++j) {
                int p = m0 + wrow + mf * 16 + l4 * 4 + j;
                h_ws[((size_t)e * HS + p) * HH + hcol] = f2bf(gelu_tanh(acc[mf][nf][j] + bias));
            }
        }
    }
}

// ---------------- Kernel 5: GEMM2 + combine ----------------
// grid (12 m-tiles, 8 n-tiles, 8 experts), 256 threads
__global__ __launch_bounds__(256, 2) void k_mlp2(
    const unsigned short* __restrict__ h_ws, const float* __restrict__ w2,
    const float* __restrict__ b2, const int* __restrict__ cnt,
    const int* __restrict__ toks, const float* __restrict__ gates,
    float* __restrict__ out) {
    int e = blockIdx.z;
    int c = cnt[e];
    int m0 = blockIdx.x * 128;
    if (m0 >= c) return;
    int n0 = blockIdx.y * 128;

    __shared__ char sA[2][8192];
    __shared__ char sB[2][8192];
    __shared__ int s_tok[128];
    __shared__ float s_gate[128];

    int tid = threadIdx.x;
    if (tid < 128) {
        int p = m0 + tid;
        s_tok[tid]  = (p < c) ? toks[e * TT + p] : 0;
        s_gate[tid] = (p < c) ? gates[e * TT + p] : 0.f;
    }

    int w = tid >> 6, lane = tid & 63;
    int l15 = lane & 15, l4 = lane >> 4;
    int wrow = (w >> 1) * 64, wcol = (w & 1) * 64;

    int ra = tid >> 1, ha = tid & 1;
    const unsigned short* srcA = h_ws + ((size_t)e * HS + m0 + ra) * HH + ha * 16;
    const float* srcB = w2 + ((size_t)e * DD + n0 + ra) * HH + ha * 16;
    int wbyte0 = SWZ_W(ra, ha * 32);
    int wbyte1 = SWZ_W(ra, ha * 32 + 16);

    f32x4 acc[4][4];
#pragma unroll
    for (int mf = 0; mf < 4; ++mf)
#pragma unroll
        for (int nf = 0; nf < 4; ++nf) acc[mf][nf] = (f32x4){0.f, 0.f, 0.f, 0.f};

    int rchunk = ((l4 ^ (l15 & 3)) * 16);

    s16x8 la0, la1; float4 lb[4];
    la0 = ((const s16x8*)srcA)[0]; la1 = ((const s16x8*)srcA)[1];
#pragma unroll
    for (int q = 0; q < 4; ++q) lb[q] = ((const float4*)srcB)[q];
    *(s16x8*)(&sA[0][wbyte0]) = la0;
    *(s16x8*)(&sA[0][wbyte1]) = la1;
    *(s16x8*)(&sB[0][wbyte0]) = cvt8(lb[0], lb[1]);
    *(s16x8*)(&sB[0][wbyte1]) = cvt8(lb[2], lb[3]);
    __syncthreads();

    const int NS = HH / 32;   // 128 K-steps
    for (int s = 0; s < NS; ++s) {
        if (s + 1 < NS) {
            const unsigned short* pa = srcA + (s + 1) * 32;
            const float* pb = srcB + (s + 1) * 32;
            la0 = ((const s16x8*)pa)[0]; la1 = ((const s16x8*)pa)[1];
#pragma unroll
            for (int q = 0; q < 4; ++q) lb[q] = ((const float4*)pb)[q];
        }
        int buf = s & 1;
        s16x8 af[4], bf[4];
#pragma unroll
        for (int mf = 0; mf < 4; ++mf) {
            int r = wrow + mf * 16 + l15;
            af[mf] = *(const s16x8*)(&sA[buf][r * 64 + rchunk]);
        }
#pragma unroll
        for (int nf = 0; nf < 4; ++nf) {
            int r = wcol + nf * 16 + l15;
            bf[nf] = *(const s16x8*)(&sB[buf][r * 64 + rchunk]);
        }
#pragma unroll
        for (int mf = 0; mf < 4; ++mf)
#pragma unroll
            for (int nf = 0; nf < 4; ++nf)
                acc[mf][nf] = __builtin_amdgcn_mfma_f32_16x16x32_bf16(af[mf], bf[nf], acc[mf][nf], 0, 0, 0);
        if (s + 1 < NS) {
            int nb = buf ^ 1;
            *(s16x8*)(&sA[nb][wbyte0]) = la0;
            *(s16x8*)(&sA[nb][wbyte1]) = la1;
            *(s16x8*)(&sB[nb][wbyte0]) = cvt8(lb[0], lb[1]);
            *(s16x8*)(&sB[nb][wbyte1]) = cvt8(lb[2], lb[3]);
        }
        __syncthreads();
    }

    // epilogue: out[tok][col] += gate * (acc + b2)
#pragma unroll
    for (int nf = 0; nf < 4; ++nf) {
        int col = n0 + wcol + nf * 16 + l15;
        float bb = b2[(size_t)e * DD + col];
#pragma unroll
        for (int mf = 0; mf < 4; ++mf) {
#pragma unroll
            for (int j = 0; j < 4; ++j) {
                int prow = wrow + mf * 16 + l4 * 4 + j;
                if (m0 + prow < c) {
                    atomicAdd(&out[(size_t)s_tok[prow] * DD + col],
                              s_gate[prow] * (acc[mf][nf][j] + bb));
                }
            }
        }
    }
}

extern "C" void kernel_launch(void* const* d_in, const int* in_sizes, int n_in,
                              void* d_out, int out_size, void* d_ws, size_t ws_size,
                              hipStream_t stream) {
    const float* x  = (const float*)d_in[0];
    const float* gw = (const float*)d_in[1];
    const float* w1 = (const float*)d_in[2];
    const float* b1 = (const float*)d_in[3];
    const float* w2 = (const float*)d_in[4];
    const float* b2 = (const float*)d_in[5];
    float* out = (float*)d_out;

    char* ws = (char*)d_ws;
    float* logits = (float*)ws;                        // 131072 B
    float* kth    = (float*)(ws + 131072);             // 4 B
    int*   cnt    = (int*)(ws + 131104);               // 32 B
    int*   toks   = (int*)(ws + 131136);               // 131072 B
    float* gates  = (float*)(ws + 262208);             // 131072 B
    unsigned short* h_ws = (unsigned short*)(ws + 1048576);  // 8*1536*4096*2 = 96 MB

    hipMemsetAsync(out, 0, (size_t)TT * DD * sizeof(float), stream);
    hipMemsetAsync(cnt, 0, EE * sizeof(int), stream);

    k_logits<<<dim3(TT / 4), dim3(256), 0, stream>>>(x, gw, logits);
    k_select<<<dim3(1), dim3(1024), 0, stream>>>(logits, kth);
    k_lists<<<dim3(TT * EE / 256), dim3(256), 0, stream>>>(logits, kth, cnt, toks, gates);
    k_mlp1<<<dim3(12, 32, 8), dim3(256), 0, stream>>>(x, w1, b1, cnt, toks, h_ws);
    k_mlp2<<<dim3(12, 8, 8), dim3(256), 0, stream>>>(h_ws, w2, b2, cnt, toks, gates, out);
}

// Round 4
// 778.556 us; speedup vs baseline: 5.0498x; 1.0493x over previous
//
#include <hip/hip_runtime.h>
#include <hip/hip_bf16.h>

// Problem constants
#define TT 4096      // tokens = B*L
#define DD 1024      // model dim
#define EE 8         // experts
#define HH 4096      // mlp hidden
#define KSEL 24576   // expert_k (1-indexed kth smallest)
#define HS  1536     // h_ws rows per expert (c_e ~ 1024 +- ~30; huge margin)

using f32x4 = __attribute__((ext_vector_type(4))) float;
using s16x8 = __attribute__((ext_vector_type(8))) short;

__device__ __forceinline__ unsigned short f2bf(float f) {
    union { __hip_bfloat16 h; unsigned short u; } v;
    v.h = __float2bfloat16(f);
    return v.u;
}

__device__ __forceinline__ float gelu_tanh(float v) {
    float v3 = v * v * v;
    return 0.5f * v * (1.0f + tanhf(0.7978845608028654f * (v + 0.044715f * v3)));
}

__device__ __forceinline__ s16x8 cvt8(float4 a, float4 b) {
    s16x8 r;
    r[0] = (short)f2bf(a.x); r[1] = (short)f2bf(a.y);
    r[2] = (short)f2bf(a.z); r[3] = (short)f2bf(a.w);
    r[4] = (short)f2bf(b.x); r[5] = (short)f2bf(b.y);
    r[6] = (short)f2bf(b.z); r[7] = (short)f2bf(b.w);
    return r;
}

// async global->LDS 16B: LDS dest = wave-uniform base + lane*16 (linear);
// swizzle is achieved by pre-swizzling the per-lane GLOBAL source (rule #21).
typedef const __attribute__((address_space(1))) unsigned int ga_u32;
typedef __attribute__((address_space(3))) unsigned int ls_u32;
__device__ __forceinline__ void gld16(const void* g, void* l) {
    __builtin_amdgcn_global_load_lds((ga_u32*)g, (ls_u32*)l, 16, 0, 0);
}

// ---------------- Kernel 1: router logits [T][E] fp32 ----------------
__global__ void k_logits(const float* __restrict__ x, const float* __restrict__ gw,
                         float* __restrict__ logits) {
    int wid = threadIdx.x >> 6, lane = threadIdx.x & 63;
    int t = blockIdx.x * 4 + wid;
    if (t >= TT) return;
    const float* xr = x + (size_t)t * DD;
    float acc[EE];
#pragma unroll
    for (int e = 0; e < EE; ++e) acc[e] = 0.f;
    for (int i = 0; i < DD / 64; ++i) {
        int d = i * 64 + lane;
        float xv = xr[d];
#pragma unroll
        for (int e = 0; e < EE; ++e) acc[e] += xv * gw[e * DD + d];
    }
#pragma unroll
    for (int e = 0; e < EE; ++e) {
        float v = acc[e];
        for (int off = 32; off; off >>= 1) v += __shfl_xor(v, off, 64);
        if (lane == 0) logits[(size_t)t * EE + e] = v;
    }
}

// ---------------- Kernel 2: exact kth smallest ----------------
__global__ void k_select(const float* __restrict__ logits, float* __restrict__ kth) {
    int tid = threadIdx.x;           // 1024 threads
    unsigned int v[32];
#pragma unroll
    for (int i = 0; i < 32; ++i) {
        unsigned int b = __float_as_uint(logits[tid + i * 1024]);
        v[i] = (b & 0x80000000u) ? ~b : (b | 0x80000000u);
    }
    __shared__ int s_cnt;
    unsigned int prefix = 0;
    for (int bit = 31; bit >= 0; --bit) {
        unsigned int cand = prefix | (1u << bit);
        int c = 0;
#pragma unroll
        for (int i = 0; i < 32; ++i) c += (v[i] < cand) ? 1 : 0;
        for (int off = 32; off; off >>= 1) c += __shfl_xor(c, off, 64);
        __syncthreads();
        if (tid == 0) s_cnt = 0;
        __syncthreads();
        if ((tid & 63) == 0) atomicAdd(&s_cnt, c);
        __syncthreads();
        if (s_cnt < KSEL) prefix = cand;
    }
    if (tid == 0) {
        unsigned int b = (prefix & 0x80000000u) ? (prefix ^ 0x80000000u) : ~prefix;
        *kth = __uint_as_float(b);
    }
}

// ---------------- Kernel 3: per-expert compact token lists ----------------
__global__ void k_lists(const float* __restrict__ logits, const float* __restrict__ kth,
                        int* __restrict__ cnt, int* __restrict__ toks,
                        float* __restrict__ gates) {
    int idx = blockIdx.x * 256 + threadIdx.x;
    float v = logits[idx];
    if (v >= *kth) {
        int e = idx & 7, t = idx >> 3;
        int p = atomicAdd(&cnt[e], 1);
        if (p < TT) { toks[e * TT + p] = t; gates[e * TT + p] = v; }
    }
}

// ---------------- Kernel: fp32 -> bf16 bulk convert ----------------
__global__ void k_cvt(const float* __restrict__ src, unsigned short* __restrict__ dst, int n8) {
    int i = blockIdx.x * blockDim.x + threadIdx.x;
    int stride = gridDim.x * blockDim.x;
    for (; i < n8; i += stride) {
        float4 a = ((const float4*)src)[2 * i];
        float4 b = ((const float4*)src)[2 * i + 1];
        ((s16x8*)dst)[i] = cvt8(a, b);
    }
}

// ================= GEMM common =================
// 128x128 tile, BK=32, 256 threads = 4 waves; wave quadrant 64x64.
// LDS row byte-stride 64; byte = r*64 + (chunk16 ^ (((r>>1)&3)<<4)).
// Bank map: every 16-lane b128 phase covers each bank-quad exactly 2x (free).
#define SWZ_W(r, cb) ((r) * 64 + ((cb) ^ ((((r) >> 1) & 3) << 4)))

// ========== FAST PATH: bf16 pre-converted weights + global_load_lds ==========

// ---------------- k_mlp1_f: h = gelu(x[toks] @ w1^T + b1) -> h_ws bf16 ----------------
// grid (12 m-tiles, 32 n-tiles, 8 experts), 256 threads
__global__ __launch_bounds__(256, 4) void k_mlp1_f(
    const unsigned short* __restrict__ xb, const unsigned short* __restrict__ w1b,
    const float* __restrict__ b1, const int* __restrict__ cnt,
    const int* __restrict__ toks, unsigned short* __restrict__ h_ws) {
    int e = blockIdx.z;
    int c = cnt[e];
    int m0 = blockIdx.x * 128;
    if (m0 >= c) return;
    int n0 = blockIdx.y * 128;

    __shared__ unsigned short sA[2][4096];   // 2 x 8KB
    __shared__ unsigned short sB[2][4096];
    __shared__ int s_tok[128];

    int tid = threadIdx.x;
    if (tid < 128) {
        int p = m0 + tid;
        s_tok[tid] = (p < c) ? toks[e * TT + p] : 0;
    }
    __syncthreads();

    int w = tid >> 6, lane = tid & 63;
    int l15 = lane & 15, l4 = lane >> 4;
    int wrow = (w >> 1) * 64, wcol = (w & 1) * 64;

    // staging: wave w stages rows [w*32, w*32+32); lane -> row sr=lane>>2, chunk (lane&3)*16
    int sr = lane >> 2;
    int ci = (lane & 3) * 16;
    int r0 = w * 32 + sr, r1 = r0 + 16;
    int sw0 = ((r0 >> 1) & 3) << 4, sw1 = ((r1 >> 1) & 3) << 4;
    const char* gA0 = (const char*)(xb + (size_t)s_tok[r0] * DD) + (ci ^ sw0);
    const char* gA1 = (const char*)(xb + (size_t)s_tok[r1] * DD) + (ci ^ sw1);
    const char* gB0 = (const char*)(w1b + ((size_t)e * HH + n0 + r0) * DD) + (ci ^ sw0);
    const char* gB1 = (const char*)(w1b + ((size_t)e * HH + n0 + r1) * DD) + (ci ^ sw1);
    char* dA = (char*)&sA[0][0] + w * 2048;   // wave-uniform LDS dest base
    char* dB = (char*)&sB[0][0] + w * 2048;

    f32x4 acc[4][4];
#pragma unroll
    for (int mf = 0; mf < 4; ++mf)
#pragma unroll
        for (int nf = 0; nf < 4; ++nf) acc[mf][nf] = (f32x4){0.f, 0.f, 0.f, 0.f};

    int rchunk = (l4 ^ ((l15 >> 1) & 3)) * 16;

    gld16(gA0, dA); gld16(gA1, dA + 1024);
    gld16(gB0, dB); gld16(gB1, dB + 1024);
    __syncthreads();

    const int NS = DD / 32;
    int buf = 0;
    for (int s = 0; s < NS; ++s) {
        if (s + 1 < NS) {
            int ko = (s + 1) * 64;
            int nb = buf ^ 1;
            gld16(gA0 + ko, dA + nb * 8192); gld16(gA1 + ko, dA + nb * 8192 + 1024);
            gld16(gB0 + ko, dB + nb * 8192); gld16(gB1 + ko, dB + nb * 8192 + 1024);
        }
        const char* bA = (const char*)&sA[buf][0];
        const char* bB = (const char*)&sB[buf][0];
        s16x8 af[4], bfr[4];
#pragma unroll
        for (int mf = 0; mf < 4; ++mf)
            af[mf] = *(const s16x8*)(bA + (wrow + mf * 16 + l15) * 64 + rchunk);
#pragma unroll
        for (int nf = 0; nf < 4; ++nf)
            bfr[nf] = *(const s16x8*)(bB + (wcol + nf * 16 + l15) * 64 + rchunk);
#pragma unroll
        for (int mf = 0; mf < 4; ++mf)
#pragma unroll
            for (int nf = 0; nf < 4; ++nf)
                acc[mf][nf] = __builtin_amdgcn_mfma_f32_16x16x32_bf16(af[mf], bfr[nf], acc[mf][nf], 0, 0, 0);
        __syncthreads();
        buf ^= 1;
    }

#pragma unroll
    for (int nf = 0; nf < 4; ++nf) {
        int hcol = n0 + wcol + nf * 16 + l15;
        float bias = b1[(size_t)e * HH + hcol];
#pragma unroll
        for (int mf = 0; mf < 4; ++mf) {
#pragma unroll
            for (int j = 0; j < 4; ++j) {
                int p = m0 + wrow + mf * 16 + l4 * 4 + j;
                h_ws[((size_t)e * HS + p) * HH + hcol] = f2bf(gelu_tanh(acc[mf][nf][j] + bias));
            }
        }
    }
}

// ---------------- k_mlp2_f: out[tok] += gate*(h @ w2^T + b2), K-split x2 ----------------
// grid (12 m-tiles, 8 n-tiles * 2 kz, 8 experts), 256 threads
__global__ __launch_bounds__(256, 4) void k_mlp2_f(
    const unsigned short* __restrict__ h_ws, const unsigned short* __restrict__ w2b,
    const float* __restrict__ b2, const int* __restrict__ cnt,
    const int* __restrict__ toks, const float* __restrict__ gates,
    float* __restrict__ out) {
    int e = blockIdx.z;
    int c = cnt[e];
    int m0 = blockIdx.x * 128;
    if (m0 >= c) return;
    int n0 = (blockIdx.y & 7) * 128;
    int kz = blockIdx.y >> 3;                 // 0 or 1
    size_t kbase = (size_t)kz * 2048;         // element offset into K=4096

    __shared__ unsigned short sA[2][4096];
    __shared__ unsigned short sB[2][4096];
    __shared__ int s_tok[128];
    __shared__ float s_gate[128];

    int tid = threadIdx.x;
    if (tid < 128) {
        int p = m0 + tid;
        s_tok[tid]  = (p < c) ? toks[e * TT + p] : 0;
        s_gate[tid] = (p < c) ? gates[e * TT + p] : 0.f;
    }

    int w = tid >> 6, lane = tid & 63;
    int l15 = lane & 15, l4 = lane >> 4;
    int wrow = (w >> 1) * 64, wcol = (w & 1) * 64;

    int sr = lane >> 2;
    int ci = (lane & 3) * 16;
    int r0 = w * 32 + sr, r1 = r0 + 16;
    int sw0 = ((r0 >> 1) & 3) << 4, sw1 = ((r1 >> 1) & 3) << 4;
    const char* gA0 = (const char*)(h_ws + ((size_t)e * HS + m0 + r0) * HH + kbase) + (ci ^ sw0);
    const char* gA1 = (const char*)(h_ws + ((size_t)e * HS + m0 + r1) * HH + kbase) + (ci ^ sw1);
    const char* gB0 = (const char*)(w2b + ((size_t)e * DD + n0 + r0) * HH + kbase) + (ci ^ sw0);
    const char* gB1 = (const char*)(w2b + ((size_t)e * DD + n0 + r1) * HH + kbase) + (ci ^ sw1);
    char* dA = (char*)&sA[0][0] + w * 2048;
    char* dB = (char*)&sB[0][0] + w * 2048;

    f32x4 acc[4][4];
#pragma unroll
    for (int mf = 0; mf < 4; ++mf)
#pragma unroll
        for (int nf = 0; nf < 4; ++nf) acc[mf][nf] = (f32x4){0.f, 0.f, 0.f, 0.f};

    int rchunk = (l4 ^ ((l15 >> 1) & 3)) * 16;

    gld16(gA0, dA); gld16(gA1, dA + 1024);
    gld16(gB0, dB); gld16(gB1, dB + 1024);
    __syncthreads();

    const int NS = 2048 / 32;   // 64 K-steps per kz
    int buf = 0;
    for (int s = 0; s < NS; ++s) {
        if (s + 1 < NS) {
            int ko = (s + 1) * 64;
            int nb = buf ^ 1;
            gld16(gA0 + ko, dA + nb * 8192); gld16(gA1 + ko, dA + nb * 8192 + 1024);
            gld16(gB0 + ko, dB + nb * 8192); gld16(gB1 + ko, dB + nb * 8192 + 1024);
        }
        const char* bA = (const char*)&sA[buf][0];
        const char* bB = (const char*)&sB[buf][0];
        s16x8 af[4], bfr[4];
#pragma unroll
        for (int mf = 0; mf < 4; ++mf)
            af[mf] = *(const s16x8*)(bA + (wrow + mf * 16 + l15) * 64 + rchunk);
#pragma unroll
        for (int nf = 0; nf < 4; ++nf)
            bfr[nf] = *(const s16x8*)(bB + (wcol + nf * 16 + l15) * 64 + rchunk);
#pragma unroll
        for (int mf = 0; mf < 4; ++mf)
#pragma unroll
            for (int nf = 0; nf < 4; ++nf)
                acc[mf][nf] = __builtin_amdgcn_mfma_f32_16x16x32_bf16(af[mf], bfr[nf], acc[mf][nf], 0, 0, 0);
        __syncthreads();
        buf ^= 1;
    }

#pragma unroll
    for (int nf = 0; nf < 4; ++nf) {
        int col = n0 + wcol + nf * 16 + l15;
        float bb = (kz == 0) ? b2[(size_t)e * DD + col] : 0.f;
#pragma unroll
        for (int mf = 0; mf < 4; ++mf) {
#pragma unroll
            for (int j = 0; j < 4; ++j) {
                int prow = wrow + mf * 16 + l4 * 4 + j;
                if (m0 + prow < c) {
                    atomicAdd(&out[(size_t)s_tok[prow] * DD + col],
                              s_gate[prow] * (acc[mf][nf][j] + bb));
                }
            }
        }
    }
}

// ========== FALLBACK PATH: reg-staged fp32 weights (round-2 structure, fixed swizzle) ==========

__global__ __launch_bounds__(256, 2) void k_mlp1(
    const float* __restrict__ x, const float* __restrict__ w1,
    const float* __restrict__ b1, const int* __restrict__ cnt,
    const int* __restrict__ toks, unsigned short* __restrict__ h_ws) {
    int e = blockIdx.z;
    int c = cnt[e];
    int m0 = blockIdx.x * 128;
    if (m0 >= c) return;
    int n0 = blockIdx.y * 128;

    __shared__ char sA[2][8192];
    __shared__ char sB[2][8192];

    int tid = threadIdx.x;
    int w = tid >> 6, lane = tid & 63;
    int l15 = lane & 15, l4 = lane >> 4;
    int wrow = (w >> 1) * 64, wcol = (w & 1) * 64;

    int ra = tid >> 1, ha = tid & 1;
    int ptok = m0 + ra;
    int tok = (ptok < c) ? toks[e * TT + ptok] : 0;
    const float* srcA = x + (size_t)tok * DD + ha * 16;
    const float* srcB = w1 + ((size_t)e * HH + n0 + ra) * DD + ha * 16;
    int wbyteA0 = SWZ_W(ra, ha * 32);
    int wbyteA1 = SWZ_W(ra, ha * 32 + 16);

    f32x4 acc[4][4];
#pragma unroll
    for (int mf = 0; mf < 4; ++mf)
#pragma unroll
        for (int nf = 0; nf < 4; ++nf) acc[mf][nf] = (f32x4){0.f, 0.f, 0.f, 0.f};

    int rchunk = (l4 ^ ((l15 >> 1) & 3)) * 16;

    float4 la[4], lb[4];
#pragma unroll
    for (int q = 0; q < 4; ++q) { la[q] = ((const float4*)srcA)[q]; lb[q] = ((const float4*)srcB)[q]; }
    *(s16x8*)(&sA[0][wbyteA0]) = cvt8(la[0], la[1]);
    *(s16x8*)(&sA[0][wbyteA1]) = cvt8(la[2], la[3]);
    *(s16x8*)(&sB[0][wbyteA0]) = cvt8(lb[0], lb[1]);
    *(s16x8*)(&sB[0][wbyteA1]) = cvt8(lb[2], lb[3]);
    __syncthreads();

    const int NS = DD / 32;
    for (int s = 0; s < NS; ++s) {
        if (s + 1 < NS) {
            const float* pa = srcA + (s + 1) * 32;
            const float* pb = srcB + (s + 1) * 32;
#pragma unroll
            for (int q = 0; q < 4; ++q) { la[q] = ((const float4*)pa)[q]; lb[q] = ((const float4*)pb)[q]; }
        }
        int buf = s & 1;
        s16x8 af[4], bfr[4];
#pragma unroll
        for (int mf = 0; mf < 4; ++mf)
            af[mf] = *(const s16x8*)(&sA[buf][(wrow + mf * 16 + l15) * 64 + rchunk]);
#pragma unroll
        for (int nf = 0; nf < 4; ++nf)
            bfr[nf] = *(const s16x8*)(&sB[buf][(wcol + nf * 16 + l15) * 64 + rchunk]);
#pragma unroll
        for (int mf = 0; mf < 4; ++mf)
#pragma unroll
            for (int nf = 0; nf < 4; ++nf)
                acc[mf][nf] = __builtin_amdgcn_mfma_f32_16x16x32_bf16(af[mf], bfr[nf], acc[mf][nf], 0, 0, 0);
        if (s + 1 < NS) {
            int nb = buf ^ 1;
            *(s16x8*)(&sA[nb][wbyteA0]) = cvt8(la[0], la[1]);
            *(s16x8*)(&sA[nb][wbyteA1]) = cvt8(la[2], la[3]);
            *(s16x8*)(&sB[nb][wbyteA0]) = cvt8(lb[0], lb[1]);
            *(s16x8*)(&sB[nb][wbyteA1]) = cvt8(lb[2], lb[3]);
        }
        __syncthreads();
    }

#pragma unroll
    for (int nf = 0; nf < 4; ++nf) {
        int hcol = n0 + wcol + nf * 16 + l15;
        float bias = b1[(size_t)e * HH + hcol];
#pragma unroll
        for (int mf = 0; mf < 4; ++mf) {
#pragma unroll
            for (int j = 0; j < 4; ++j) {
                int p = m0 + wrow + mf * 16 + l4 * 4 + j;
                h_ws[((size_t)e * HS + p) * HH + hcol] = f2bf(gelu_tanh(acc[mf][nf][j] + bias));
            }
        }
    }
}

__global__ __launch_bounds__(256, 2) void k_mlp2(
    const unsigned short* __restrict__ h_ws, const float* __restrict__ w2,
    const float* __restrict__ b2, const int* __restrict__ cnt,
    const int* __restrict__ toks, const float* __restrict__ gates,
    float* __restrict__ out) {
    int e = blockIdx.z;
    int c = cnt[e];
    int m0 = blockIdx.x * 128;
    if (m0 >= c) return;
    int n0 = blockIdx.y * 128;

    __shared__ char sA[2][8192];
    __shared__ char sB[2][8192];
    __shared__ int s_tok[128];
    __shared__ float s_gate[128];

    int tid = threadIdx.x;
    if (tid < 128) {
        int p = m0 + tid;
        s_tok[tid]  = (p < c) ? toks[e * TT + p] : 0;
        s_gate[tid] = (p < c) ? gates[e * TT + p] : 0.f;
    }

    int w = tid >> 6, lane = tid & 63;
    int l15 = lane & 15, l4 = lane >> 4;
    int wrow = (w >> 1) * 64, wcol = (w & 1) * 64;

    int ra = tid >> 1, ha = tid & 1;
    const unsigned short* srcA = h_ws + ((size_t)e * HS + m0 + ra) * HH + ha * 16;
    const float* srcB = w2 + ((size_t)e * DD + n0 + ra) * HH + ha * 16;
    int wbyte0 = SWZ_W(ra, ha * 32);
    int wbyte1 = SWZ_W(ra, ha * 32 + 16);

    f32x4 acc[4][4];
#pragma unroll
    for (int mf = 0; mf < 4; ++mf)
#pragma unroll
        for (int nf = 0; nf < 4; ++nf) acc[mf][nf] = (f32x4){0.f, 0.f, 0.f, 0.f};

    int rchunk = (l4 ^ ((l15 >> 1) & 3)) * 16;

    s16x8 la0, la1; float4 lb[4];
    la0 = ((const s16x8*)srcA)[0]; la1 = ((const s16x8*)srcA)[1];
#pragma unroll
    for (int q = 0; q < 4; ++q) lb[q] = ((const float4*)srcB)[q];
    *(s16x8*)(&sA[0][wbyte0]) = la0;
    *(s16x8*)(&sA[0][wbyte1]) = la1;
    *(s16x8*)(&sB[0][wbyte0]) = cvt8(lb[0], lb[1]);
    *(s16x8*)(&sB[0][wbyte1]) = cvt8(lb[2], lb[3]);
    __syncthreads();

    const int NS = HH / 32;
    for (int s = 0; s < NS; ++s) {
        if (s + 1 < NS) {
            const unsigned short* pa = srcA + (s + 1) * 32;
            const float* pb = srcB + (s + 1) * 32;
            la0 = ((const s16x8*)pa)[0]; la1 = ((const s16x8*)pa)[1];
#pragma unroll
            for (int q = 0; q < 4; ++q) lb[q] = ((const float4*)pb)[q];
        }
        int buf = s & 1;
        s16x8 af[4], bfr[4];
#pragma unroll
        for (int mf = 0; mf < 4; ++mf)
            af[mf] = *(const s16x8*)(&sA[buf][(wrow + mf * 16 + l15) * 64 + rchunk]);
#pragma unroll
        for (int nf = 0; nf < 4; ++nf)
            bfr[nf] = *(const s16x8*)(&sB[buf][(wcol + nf * 16 + l15) * 64 + rchunk]);
#pragma unroll
        for (int mf = 0; mf < 4; ++mf)
#pragma unroll
            for (int nf = 0; nf < 4; ++nf)
                acc[mf][nf] = __builtin_amdgcn_mfma_f32_16x16x32_bf16(af[mf], bfr[nf], acc[mf][nf], 0, 0, 0);
        if (s + 1 < NS) {
            int nb = buf ^ 1;
            *(s16x8*)(&sA[nb][wbyte0]) = la0;
            *(s16x8*)(&sA[nb][wbyte1]) = la1;
            *(s16x8*)(&sB[nb][wbyte0]) = cvt8(lb[0], lb[1]);
            *(s16x8*)(&sB[nb][wbyte1]) = cvt8(lb[2], lb[3]);
        }
        __syncthreads();
    }

#pragma unroll
    for (int nf = 0; nf < 4; ++nf) {
        int col = n0 + wcol + nf * 16 + l15;
        float bb = b2[(size_t)e * DD + col];
#pragma unroll
        for (int mf = 0; mf < 4; ++mf) {
#pragma unroll
            for (int j = 0; j < 4; ++j) {
                int prow = wrow + mf * 16 + l4 * 4 + j;
                if (m0 + prow < c) {
                    atomicAdd(&out[(size_t)s_tok[prow] * DD + col],
                              s_gate[prow] * (acc[mf][nf][j] + bb));
                }
            }
        }
    }
}

extern "C" void kernel_launch(void* const* d_in, const int* in_sizes, int n_in,
                              void* d_out, int out_size, void* d_ws, size_t ws_size,
                              hipStream_t stream) {
    const float* x  = (const float*)d_in[0];
    const float* gw = (const float*)d_in[1];
    const float* w1 = (const float*)d_in[2];
    const float* b1 = (const float*)d_in[3];
    const float* w2 = (const float*)d_in[4];
    const float* b2 = (const float*)d_in[5];
    float* out = (float*)d_out;

    char* ws = (char*)d_ws;
    float* logits = (float*)ws;                        // 131072 B
    float* kth    = (float*)(ws + 131072);
    int*   cnt    = (int*)(ws + 131104);
    int*   toks   = (int*)(ws + 131136);               // 131072 B
    float* gates  = (float*)(ws + 262208);             // 131072 B

    hipMemsetAsync(out, 0, (size_t)TT * DD * sizeof(float), stream);
    hipMemsetAsync(cnt, 0, EE * sizeof(int), stream);

    k_logits<<<dim3(TT / 4), dim3(256), 0, stream>>>(x, gw, logits);
    k_select<<<dim3(1), dim3(1024), 0, stream>>>(logits, kth);
    k_lists<<<dim3(TT * EE / 256), dim3(256), 0, stream>>>(logits, kth, cnt, toks, gates);

    const size_t OFF_XB  = 1048576;
    const size_t OFF_W1B = OFF_XB + (size_t)TT * DD * 2;            // 8 MB of xb
    const size_t OFF_W2B = OFF_W1B + (size_t)EE * HH * DD * 2;      // 64 MB of w1b
    const size_t OFF_H   = OFF_W2B + (size_t)EE * DD * HH * 2;      // 64 MB of w2b
    const size_t NEEDED  = OFF_H + (size_t)EE * HS * HH * 2;        // 96 MB of h_ws

    if (ws_size >= NEEDED) {
        unsigned short* xb   = (unsigned short*)(ws + OFF_XB);
        unsigned short* w1b  = (unsigned short*)(ws + OFF_W1B);
        unsigned short* w2b  = (unsigned short*)(ws + OFF_W2B);
        unsigned short* h_ws = (unsigned short*)(ws + OFF_H);
        k_cvt<<<dim3(2048), dim3(256), 0, stream>>>(x, xb, TT * DD / 8);
        k_cvt<<<dim3(2048), dim3(256), 0, stream>>>(w1, w1b, EE * HH * DD / 8);
        k_cvt<<<dim3(2048), dim3(256), 0, stream>>>(w2, w2b, EE * DD * HH / 8);
        k_mlp1_f<<<dim3(12, 32, 8), dim3(256), 0, stream>>>(xb, w1b, b1, cnt, toks, h_ws);
        k_mlp2_f<<<dim3(12, 16, 8), dim3(256), 0, stream>>>(h_ws, w2b, b2, cnt, toks, gates, out);
    } else {
        unsigned short* h_ws = (unsigned short*)(ws + 1048576);
        k_mlp1<<<dim3(12, 32, 8), dim3(256), 0, stream>>>(x, w1, b1, cnt, toks, h_ws);
        k_mlp2<<<dim3(12, 8, 8), dim3(256), 0, stream>>>(h_ws, w2, b2, cnt, toks, gates, out);
    }
}